// Round 1
// baseline (1733.335 us; speedup 1.0000x reference)
//
#include <hip/hip_runtime.h>

#define NN 100000
#define NE 1600000
#define NG 64
#define HIDC 128
#define INC 9
#define OUTC 2

// ---------- degree / dinv ----------
__global__ void k_deg_init(float* deg) {
    int i = blockIdx.x * 256 + threadIdx.x;
    if (i < NN) deg[i] = 1.0f;  // self-loop
}

__global__ void k_deg_edges(const int* __restrict__ col, float* deg) {
    int e = blockIdx.x * 256 + threadIdx.x;
    if (e < NE) unsafeAtomicAdd(&deg[col[e]], 1.0f);
}

__global__ void k_dinv(float* deg) {
    int i = blockIdx.x * 256 + threadIdx.x;
    if (i < NN) deg[i] = rsqrtf(deg[i]);  // deg >= 1 always (self-loops)
}

// ---------- layer-1 dense: A = x@W1 ; B = A * dinv^2 (self-loop init) ----------
__global__ __launch_bounds__(256) void k_xw1(const float* __restrict__ x,
                                             const float* __restrict__ W1,
                                             const float* __restrict__ dinv,
                                             float* __restrict__ A,
                                             float* __restrict__ B) {
    int tid = threadIdx.x;
    int i = blockIdx.x * 2 + (tid >> 7);
    int f = tid & 127;
    if (i >= NN) return;
    float di = dinv[i];
    float acc = 0.f;
#pragma unroll
    for (int k = 0; k < INC; ++k) acc += x[i * INC + k] * W1[k * HIDC + f];
    A[(long)i * HIDC + f] = acc;
    B[(long)i * HIDC + f] = acc * di * di;
}

// ---------- edge scatter: B[col] += A[row] * dinv[row]*dinv[col] ----------
__global__ __launch_bounds__(256) void k_edge(const int* __restrict__ row,
                                              const int* __restrict__ col,
                                              const float* __restrict__ dinv,
                                              const float* __restrict__ A,
                                              float* __restrict__ B) {
    int tid = threadIdx.x;
    long e = (long)blockIdx.x * 2 + (tid >> 7);
    int f = tid & 127;
    if (e >= NE) return;
    int r = row[e], c = col[e];
    float v = A[(long)r * HIDC + f] * dinv[r] * dinv[c];
    unsafeAtomicAdd(&B[(long)c * HIDC + f], v);
}

// ---------- layer-2 dense: h1=relu(B+b1); A=h1@W2; B=A*dinv^2 (in place on B) ----------
__global__ __launch_bounds__(256) void k_layer2(const float* __restrict__ Bin,
                                                const float* __restrict__ b1,
                                                const float* __restrict__ W2,
                                                const float* __restrict__ dinv,
                                                float* __restrict__ A,
                                                float* __restrict__ Bout) {
    __shared__ float W2s[HIDC * HIDC];  // 64 KB
    __shared__ float hrow[2][HIDC];
    int tid = threadIdx.x;
    int j = tid >> 7, f = tid & 127;
    for (int k = tid; k < HIDC * HIDC; k += 256) W2s[k] = W2[k];
    for (int base = blockIdx.x * 2; base < NN; base += gridDim.x * 2) {
        int i = base + j;
        __syncthreads();
        if (i < NN) {
            float h = Bin[(long)i * HIDC + f] + b1[f];
            hrow[j][f] = h > 0.f ? h : 0.f;
        }
        __syncthreads();
        if (i < NN) {
            float a0 = 0, a1 = 0, a2 = 0, a3 = 0;
            for (int k = 0; k < HIDC; k += 4) {
                a0 += hrow[j][k + 0] * W2s[(k + 0) * HIDC + f];
                a1 += hrow[j][k + 1] * W2s[(k + 1) * HIDC + f];
                a2 += hrow[j][k + 2] * W2s[(k + 2) * HIDC + f];
                a3 += hrow[j][k + 3] * W2s[(k + 3) * HIDC + f];
            }
            float acc = (a0 + a1) + (a2 + a3);
            float di = dinv[i];
            A[(long)i * HIDC + f] = acc;
            Bout[(long)i * HIDC + f] = acc * di * di;  // row-exclusive in-place OK
        }
    }
}

// ---------- pooling (batch sorted -> run-length local accumulate) ----------
__global__ void k_pool_init(float* pooled, float* cnt) {
    int i = blockIdx.x * 256 + threadIdx.x;
    if (i < NG * HIDC) pooled[i] = 0.f;
    if (i < NG) cnt[i] = 0.f;
}

__global__ __launch_bounds__(128) void k_pool(const float* __restrict__ B,
                                              const float* __restrict__ b2,
                                              const int* __restrict__ batch,
                                              float* pooled, float* cnt) {
    int f = threadIdx.x;
    int start = blockIdx.x * 64;
    int end = start + 64 < NN ? start + 64 : NN;
    float sum = 0.f;
    int gcur = -1, cl = 0;
    for (int i = start; i < end; ++i) {
        int g = batch[i];
        if (g != gcur) {
            if (gcur >= 0) {
                unsafeAtomicAdd(&pooled[gcur * HIDC + f], sum);
                if (f == 0) unsafeAtomicAdd(&cnt[gcur], (float)cl);
            }
            gcur = g; sum = 0.f; cl = 0;
        }
        float h = B[(long)i * HIDC + f] + b2[f];
        sum += h > 0.f ? h : 0.f;
        cl++;
    }
    if (gcur >= 0) {
        unsafeAtomicAdd(&pooled[gcur * HIDC + f], sum);
        if (f == 0) unsafeAtomicAdd(&cnt[gcur], (float)cl);
    }
}

// ---------- head: out[g] = (pooled[g]/cnt[g]) @ Wc + bc ----------
__global__ __launch_bounds__(128) void k_final(const float* __restrict__ pooled,
                                               const float* __restrict__ cnt,
                                               const float* __restrict__ Wc,
                                               const float* __restrict__ bc,
                                               float* __restrict__ out) {
    __shared__ float v0s[HIDC], v1s[HIDC];
    int g = blockIdx.x, f = threadIdx.x;
    float c = cnt[g]; c = c > 1.f ? c : 1.f;
    float val = pooled[g * HIDC + f] / c;
    v0s[f] = val * Wc[f * OUTC + 0];
    v1s[f] = val * Wc[f * OUTC + 1];
    __syncthreads();
    if (f < 2) {
        const float* arr = (f == 0) ? v0s : v1s;
        float s = 0.f;
        for (int k = 0; k < HIDC; ++k) s += arr[k];
        out[g * OUTC + f] = s + bc[f];
    }
}

extern "C" void kernel_launch(void* const* d_in, const int* in_sizes, int n_in,
                              void* d_out, int out_size, void* d_ws, size_t ws_size,
                              hipStream_t stream) {
    const float* x     = (const float*)d_in[0];
    const int*   ei    = (const int*)d_in[1];   // [2, NE] int32
    const int*   batch = (const int*)d_in[2];
    const float* W1    = (const float*)d_in[3];
    const float* b1    = (const float*)d_in[4];
    const float* W2    = (const float*)d_in[5];
    const float* b2    = (const float*)d_in[6];
    const float* Wc    = (const float*)d_in[7];
    const float* bc    = (const float*)d_in[8];
    float* out = (float*)d_out;

    char* ws = (char*)d_ws;
    size_t off = 0;
    auto alloc = [&](size_t bytes) { void* p = ws + off; off += (bytes + 255) / 256 * 256; return p; };
    float* A      = (float*)alloc((size_t)NN * HIDC * 4);
    float* B      = (float*)alloc((size_t)NN * HIDC * 4);
    float* dinv   = (float*)alloc((size_t)NN * 4);
    float* pooled = (float*)alloc((size_t)NG * HIDC * 4);
    float* cnt    = (float*)alloc((size_t)NG * 4);

    const int* row = ei;        // sources
    const int* col = ei + NE;   // targets

    k_deg_init<<<(NN + 255) / 256, 256, 0, stream>>>(dinv);
    k_deg_edges<<<(NE + 255) / 256, 256, 0, stream>>>(col, dinv);
    k_dinv<<<(NN + 255) / 256, 256, 0, stream>>>(dinv);

    // layer 1
    k_xw1<<<(NN + 1) / 2, 256, 0, stream>>>(x, W1, dinv, A, B);
    k_edge<<<NE / 2, 256, 0, stream>>>(row, col, dinv, A, B);

    // layer 2 (relu+bias fused into GEMM; B overwritten row-exclusively)
    k_layer2<<<512, 256, 0, stream>>>(B, b1, W2, dinv, A, B);
    k_edge<<<NE / 2, 256, 0, stream>>>(row, col, dinv, A, B);

    // pool + head
    k_pool_init<<<(NG * HIDC + 255) / 256, 256, 0, stream>>>(pooled, cnt);
    k_pool<<<(NN + 63) / 64, 128, 0, stream>>>(B, b2, batch, pooled, cnt);
    k_final<<<NG, 128, 0, stream>>>(pooled, cnt, Wc, bc, out);
}

// Round 2
// 968.678 us; speedup vs baseline: 1.7894x; 1.7894x over previous
//
#include <hip/hip_runtime.h>

#define NN 100000
#define NE 1600000
#define NG 64
#define HIDC 128
#define INC 9
#define OUTC 2

// ---------------- CSR build: counting sort by target (col) ----------------
__global__ void k_zero(int* counts) {
    int i = blockIdx.x * 256 + threadIdx.x;
    if (i < NN) counts[i] = 0;
}

__global__ void k_hist(const int* __restrict__ col, int* counts) {
    int e = blockIdx.x * 256 + threadIdx.x;
    if (e < NE) atomicAdd(&counts[col[e]], 1);
}

__global__ void k_dinv(const int* __restrict__ counts, float* dinv) {
    int i = blockIdx.x * 256 + threadIdx.x;
    if (i < NN) dinv[i] = rsqrtf((float)(counts[i] + 1));  // +1 self-loop
}

// single-block exclusive scan of counts[NN] -> offsets[NN+1], cursor[NN]
__global__ __launch_bounds__(1024) void k_scan(const int* __restrict__ counts,
                                               int* __restrict__ offsets,
                                               int* __restrict__ cursor) {
    __shared__ int lds[1024];
    const int t = threadIdx.x;
    const int CH = (NN + 1023) / 1024;  // 98
    int s = 0;
    for (int k = 0; k < CH; ++k) {
        int idx = t * CH + k;
        if (idx < NN) s += counts[idx];
    }
    lds[t] = s;
    __syncthreads();
    for (int d = 1; d < 1024; d <<= 1) {
        int v = (t >= d) ? lds[t - d] : 0;
        __syncthreads();
        lds[t] += v;
        __syncthreads();
    }
    int p = (t == 0) ? 0 : lds[t - 1];
    for (int k = 0; k < CH; ++k) {
        int idx = t * CH + k;
        if (idx < NN) {
            offsets[idx] = p;
            cursor[idx] = p;
            p += counts[idx];
        }
    }
    if (t == 0) offsets[NN] = lds[1023];
}

__global__ void k_fill(const int* __restrict__ row, const int* __restrict__ col,
                       int* cursor, int* __restrict__ csr_src) {
    int e = blockIdx.x * 256 + threadIdx.x;
    if (e < NE) {
        int p = atomicAdd(&cursor[col[e]], 1);
        csr_src[p] = row[e];
    }
}

// ---------------- layer-1 dense: Ap = (x@W1) * dinv ----------------
__global__ __launch_bounds__(256) void k_xw1(const float* __restrict__ x,
                                             const float* __restrict__ W1,
                                             const float* __restrict__ dinv,
                                             float* __restrict__ Ap) {
    int tid = threadIdx.x;
    int i = blockIdx.x * 2 + (tid >> 7);
    int f = tid & 127;
    if (i >= NN) return;
    float acc = 0.f;
#pragma unroll
    for (int k = 0; k < INC; ++k) acc += x[i * INC + k] * W1[k * HIDC + f];
    Ap[(long)i * HIDC + f] = acc * dinv[i];
}

// ---------------- gather: B[i] = dinv[i] * (Ap[i] + sum_{e in} Ap[src_e]) ----------------
// one 64-lane wave per node, float2 per lane (64*8B = 512B row)
__global__ __launch_bounds__(256) void k_gather(const float* __restrict__ Ap,
                                                const int* __restrict__ csr_src,
                                                const int* __restrict__ offsets,
                                                const float* __restrict__ dinv,
                                                float* __restrict__ B) {
    int i = (blockIdx.x * 256 + threadIdx.x) >> 6;  // node = global wave id
    if (i >= NN) return;
    int lane = threadIdx.x & 63;
    const float2* Ap2 = (const float2*)Ap;
    long base = (long)i * 64 + lane;
    float2 a = Ap2[base];
    float acc0 = a.x, acc1 = a.y;
    int beg = offsets[i], end = offsets[i + 1];
    int e = beg;
    for (; e + 4 <= end; e += 4) {
        int s0 = csr_src[e], s1 = csr_src[e + 1], s2 = csr_src[e + 2], s3 = csr_src[e + 3];
        float2 v0 = Ap2[(long)s0 * 64 + lane];
        float2 v1 = Ap2[(long)s1 * 64 + lane];
        float2 v2 = Ap2[(long)s2 * 64 + lane];
        float2 v3 = Ap2[(long)s3 * 64 + lane];
        acc0 += (v0.x + v1.x) + (v2.x + v3.x);
        acc1 += (v0.y + v1.y) + (v2.y + v3.y);
    }
    for (; e < end; ++e) {
        int s = csr_src[e];
        float2 v = Ap2[(long)s * 64 + lane];
        acc0 += v.x;
        acc1 += v.y;
    }
    float di = dinv[i];
    float2 o;
    o.x = acc0 * di;
    o.y = acc1 * di;
    ((float2*)B)[base] = o;
}

// ---------------- layer-2 dense: h=relu(B+b1); Ap = (h@W2)*dinv ----------------
__global__ __launch_bounds__(256) void k_layer2(const float* __restrict__ Bin,
                                                const float* __restrict__ b1,
                                                const float* __restrict__ W2,
                                                const float* __restrict__ dinv,
                                                float* __restrict__ Ap) {
    __shared__ float W2s[HIDC * HIDC];  // 64 KB
    __shared__ float hrow[2][HIDC];
    int tid = threadIdx.x;
    int j = tid >> 7, f = tid & 127;
    for (int k = tid; k < HIDC * HIDC; k += 256) W2s[k] = W2[k];
    for (int base = blockIdx.x * 2; base < NN; base += gridDim.x * 2) {
        int i = base + j;
        __syncthreads();
        if (i < NN) {
            float h = Bin[(long)i * HIDC + f] + b1[f];
            hrow[j][f] = h > 0.f ? h : 0.f;
        }
        __syncthreads();
        if (i < NN) {
            float a0 = 0, a1 = 0, a2 = 0, a3 = 0;
            for (int k = 0; k < HIDC; k += 4) {
                a0 += hrow[j][k + 0] * W2s[(k + 0) * HIDC + f];
                a1 += hrow[j][k + 1] * W2s[(k + 1) * HIDC + f];
                a2 += hrow[j][k + 2] * W2s[(k + 2) * HIDC + f];
                a3 += hrow[j][k + 3] * W2s[(k + 3) * HIDC + f];
            }
            float acc = (a0 + a1) + (a2 + a3);
            Ap[(long)i * HIDC + f] = acc * dinv[i];
        }
    }
}

// ---------------- pooling (batch sorted -> run-length local accumulate) ----------------
__global__ void k_pool_init(float* pooled, float* cnt) {
    int i = blockIdx.x * 256 + threadIdx.x;
    if (i < NG * HIDC) pooled[i] = 0.f;
    if (i < NG) cnt[i] = 0.f;
}

__global__ __launch_bounds__(128) void k_pool(const float* __restrict__ B,
                                              const float* __restrict__ b2,
                                              const int* __restrict__ batch,
                                              float* pooled, float* cnt) {
    int f = threadIdx.x;
    int start = blockIdx.x * 64;
    int end = start + 64 < NN ? start + 64 : NN;
    float sum = 0.f;
    int gcur = -1, cl = 0;
    for (int i = start; i < end; ++i) {
        int g = batch[i];
        if (g != gcur) {
            if (gcur >= 0) {
                unsafeAtomicAdd(&pooled[gcur * HIDC + f], sum);
                if (f == 0) unsafeAtomicAdd(&cnt[gcur], (float)cl);
            }
            gcur = g; sum = 0.f; cl = 0;
        }
        float h = B[(long)i * HIDC + f] + b2[f];
        sum += h > 0.f ? h : 0.f;
        cl++;
    }
    if (gcur >= 0) {
        unsafeAtomicAdd(&pooled[gcur * HIDC + f], sum);
        if (f == 0) unsafeAtomicAdd(&cnt[gcur], (float)cl);
    }
}

// ---------------- head ----------------
__global__ __launch_bounds__(128) void k_final(const float* __restrict__ pooled,
                                               const float* __restrict__ cnt,
                                               const float* __restrict__ Wc,
                                               const float* __restrict__ bc,
                                               float* __restrict__ out) {
    __shared__ float v0s[HIDC], v1s[HIDC];
    int g = blockIdx.x, f = threadIdx.x;
    float c = cnt[g]; c = c > 1.f ? c : 1.f;
    float val = pooled[g * HIDC + f] / c;
    v0s[f] = val * Wc[f * OUTC + 0];
    v1s[f] = val * Wc[f * OUTC + 1];
    __syncthreads();
    if (f < 2) {
        const float* arr = (f == 0) ? v0s : v1s;
        float s = 0.f;
        for (int k = 0; k < HIDC; ++k) s += arr[k];
        out[g * OUTC + f] = s + bc[f];
    }
}

extern "C" void kernel_launch(void* const* d_in, const int* in_sizes, int n_in,
                              void* d_out, int out_size, void* d_ws, size_t ws_size,
                              hipStream_t stream) {
    const float* x     = (const float*)d_in[0];
    const int*   ei    = (const int*)d_in[1];   // [2, NE] int32
    const int*   batch = (const int*)d_in[2];
    const float* W1    = (const float*)d_in[3];
    const float* b1    = (const float*)d_in[4];
    const float* W2    = (const float*)d_in[5];
    const float* b2    = (const float*)d_in[6];
    const float* Wc    = (const float*)d_in[7];
    const float* bc    = (const float*)d_in[8];
    float* out = (float*)d_out;

    char* ws = (char*)d_ws;
    size_t off = 0;
    auto alloc = [&](size_t bytes) { void* p = ws + off; off += (bytes + 255) / 256 * 256; return p; };
    float* Ap      = (float*)alloc((size_t)NN * HIDC * 4);
    float* B       = (float*)alloc((size_t)NN * HIDC * 4);
    float* dinv    = (float*)alloc((size_t)NN * 4);
    int*   counts  = (int*)alloc((size_t)NN * 4);
    int*   offsets = (int*)alloc((size_t)(NN + 1) * 4);
    int*   cursor  = (int*)alloc((size_t)NN * 4);
    int*   csr_src = (int*)alloc((size_t)NE * 4);
    float* pooled  = (float*)alloc((size_t)NG * HIDC * 4);
    float* cnt     = (float*)alloc((size_t)NG * 4);

    const int* row = ei;        // sources
    const int* col = ei + NE;   // targets

    // CSR build (by target)
    k_zero<<<(NN + 255) / 256, 256, 0, stream>>>(counts);
    k_hist<<<(NE + 255) / 256, 256, 0, stream>>>(col, counts);
    k_dinv<<<(NN + 255) / 256, 256, 0, stream>>>(counts, dinv);
    k_scan<<<1, 1024, 0, stream>>>(counts, offsets, cursor);
    k_fill<<<(NE + 255) / 256, 256, 0, stream>>>(row, col, cursor, csr_src);

    // layer 1
    k_xw1<<<(NN + 1) / 2, 256, 0, stream>>>(x, W1, dinv, Ap);
    k_gather<<<(NN * 64 + 255) / 256, 256, 0, stream>>>(Ap, csr_src, offsets, dinv, B);

    // layer 2
    k_layer2<<<512, 256, 0, stream>>>(B, b1, W2, dinv, Ap);
    k_gather<<<(NN * 64 + 255) / 256, 256, 0, stream>>>(Ap, csr_src, offsets, dinv, B);

    // pool + head
    k_pool_init<<<(NG * HIDC + 255) / 256, 256, 0, stream>>>(pooled, cnt);
    k_pool<<<(NN + 63) / 64, 128, 0, stream>>>(B, b2, batch, pooled, cnt);
    k_final<<<NG, 128, 0, stream>>>(pooled, cnt, Wc, bc, out);
}

// Round 3
// 716.605 us; speedup vs baseline: 2.4188x; 1.3518x over previous
//
#include <hip/hip_runtime.h>

#define NN 100000
#define NE 1600000
#define NG 64
#define HIDC 128
#define INC 9
#define OUTC 2
#define SCAN_CHUNK 1024
#define NB_SCAN ((NN + SCAN_CHUNK - 1) / SCAN_CHUNK)  // 98

// ---------------- CSR build: counting sort by target (col) ----------------
__global__ void k_zero(int* counts) {
    int i = blockIdx.x * 256 + threadIdx.x;
    if (i < NN) counts[i] = 0;
}

__global__ void k_hist(const int* __restrict__ col, int* counts) {
    int e = blockIdx.x * 256 + threadIdx.x;
    if (e < NE) atomicAdd(&counts[col[e]], 1);
}

__global__ void k_dinv(const int* __restrict__ counts, float* dinv) {
    int i = blockIdx.x * 256 + threadIdx.x;
    if (i < NN) dinv[i] = rsqrtf((float)(counts[i] + 1));  // +1 self-loop
}

// ---- 3-phase scan ----
__global__ __launch_bounds__(256) void k_scanA(const int* __restrict__ counts, int* __restrict__ bsum) {
    __shared__ int lds[256];
    int b = blockIdx.x, t = threadIdx.x;
    int idx = b * SCAN_CHUNK + t * 4;
    int s = 0;
#pragma unroll
    for (int j = 0; j < 4; ++j)
        if (idx + j < NN) s += counts[idx + j];
    lds[t] = s;
    __syncthreads();
    for (int d = 128; d > 0; d >>= 1) {
        if (t < d) lds[t] += lds[t + d];
        __syncthreads();
    }
    if (t == 0) bsum[b] = lds[0];
}

__global__ __launch_bounds__(128) void k_scanB(const int* __restrict__ bsum,
                                               int* __restrict__ boff,
                                               int* __restrict__ offsets) {
    __shared__ int lds[128];
    int t = threadIdx.x;
    int v = (t < NB_SCAN) ? bsum[t] : 0;
    lds[t] = v;
    __syncthreads();
    for (int d = 1; d < 128; d <<= 1) {
        int u = (t >= d) ? lds[t - d] : 0;
        __syncthreads();
        lds[t] += u;
        __syncthreads();
    }
    if (t < NB_SCAN) boff[t] = lds[t] - v;  // exclusive
    if (t == NB_SCAN - 1) offsets[NN] = lds[t];
}

__global__ __launch_bounds__(256) void k_scanC(const int* __restrict__ counts,
                                               const int* __restrict__ boff,
                                               int* __restrict__ offsets,
                                               int* __restrict__ cursor) {
    __shared__ int lds[256];
    int b = blockIdx.x, t = threadIdx.x;
    int idx = b * SCAN_CHUNK + t * 4;
    int c[4];
#pragma unroll
    for (int j = 0; j < 4; ++j) c[j] = (idx + j < NN) ? counts[idx + j] : 0;
    int tot = c[0] + c[1] + c[2] + c[3];
    lds[t] = tot;
    __syncthreads();
    for (int d = 1; d < 256; d <<= 1) {
        int u = (t >= d) ? lds[t - d] : 0;
        __syncthreads();
        lds[t] += u;
        __syncthreads();
    }
    int p = boff[b] + lds[t] - tot;
#pragma unroll
    for (int j = 0; j < 4; ++j) {
        if (idx + j < NN) {
            offsets[idx + j] = p;
            cursor[idx + j] = p;
            p += c[j];
        }
    }
}

__global__ void k_fill(const int* __restrict__ row, const int* __restrict__ col,
                       int* cursor, int* __restrict__ csr_src) {
    int e = blockIdx.x * 256 + threadIdx.x;
    if (e < NE) {
        int p = atomicAdd(&cursor[col[e]], 1);
        csr_src[p] = row[e];
    }
}

// ---------------- layer-1 dense: Ap = (x@W1) * dinv ----------------
__global__ __launch_bounds__(256) void k_xw1(const float* __restrict__ x,
                                             const float* __restrict__ W1,
                                             const float* __restrict__ dinv,
                                             float* __restrict__ Ap) {
    int tid = threadIdx.x;
    int i = blockIdx.x * 2 + (tid >> 7);
    int f = tid & 127;
    if (i >= NN) return;
    float acc = 0.f;
#pragma unroll
    for (int k = 0; k < INC; ++k) acc += x[i * INC + k] * W1[k * HIDC + f];
    Ap[(long)i * HIDC + f] = acc * dinv[i];
}

// ---------------- gather: B[i] = dinv[i] * (Ap[i] + sum_{e in} Ap[src_e]) ----------------
__global__ __launch_bounds__(256) void k_gather(const float* __restrict__ Ap,
                                                const int* __restrict__ csr_src,
                                                const int* __restrict__ offsets,
                                                const float* __restrict__ dinv,
                                                float* __restrict__ B) {
    int i = (blockIdx.x * 256 + threadIdx.x) >> 6;  // node = global wave id
    if (i >= NN) return;
    int lane = threadIdx.x & 63;
    const float2* Ap2 = (const float2*)Ap;
    long base = (long)i * 64 + lane;
    float2 a = Ap2[base];
    float acc0 = a.x, acc1 = a.y;
    int beg = offsets[i], end = offsets[i + 1];
    int e = beg;
    for (; e + 4 <= end; e += 4) {
        int s0 = csr_src[e], s1 = csr_src[e + 1], s2 = csr_src[e + 2], s3 = csr_src[e + 3];
        float2 v0 = Ap2[(long)s0 * 64 + lane];
        float2 v1 = Ap2[(long)s1 * 64 + lane];
        float2 v2 = Ap2[(long)s2 * 64 + lane];
        float2 v3 = Ap2[(long)s3 * 64 + lane];
        acc0 += (v0.x + v1.x) + (v2.x + v3.x);
        acc1 += (v0.y + v1.y) + (v2.y + v3.y);
    }
    for (; e < end; ++e) {
        int s = csr_src[e];
        float2 v = Ap2[(long)s * 64 + lane];
        acc0 += v.x;
        acc1 += v.y;
    }
    float di = dinv[i];
    float2 o;
    o.x = acc0 * di;
    o.y = acc1 * di;
    ((float2*)B)[base] = o;
}

// ---------------- layer-2 dense: h=relu(B+b1); Ap = (h@W2)*dinv ----------------
__global__ __launch_bounds__(256) void k_layer2(const float* __restrict__ Bin,
                                                const float* __restrict__ b1,
                                                const float* __restrict__ W2,
                                                const float* __restrict__ dinv,
                                                float* __restrict__ Ap) {
    __shared__ float W2s[HIDC * HIDC];  // 64 KB
    __shared__ float hrow[2][HIDC];
    int tid = threadIdx.x;
    int j = tid >> 7, f = tid & 127;
    for (int k = tid; k < HIDC * HIDC; k += 256) W2s[k] = W2[k];
    for (int base = blockIdx.x * 2; base < NN; base += gridDim.x * 2) {
        int i = base + j;
        __syncthreads();
        if (i < NN) {
            float h = Bin[(long)i * HIDC + f] + b1[f];
            hrow[j][f] = h > 0.f ? h : 0.f;
        }
        __syncthreads();
        if (i < NN) {
            float a0 = 0, a1 = 0, a2 = 0, a3 = 0;
            for (int k = 0; k < HIDC; k += 4) {
                a0 += hrow[j][k + 0] * W2s[(k + 0) * HIDC + f];
                a1 += hrow[j][k + 1] * W2s[(k + 1) * HIDC + f];
                a2 += hrow[j][k + 2] * W2s[(k + 2) * HIDC + f];
                a3 += hrow[j][k + 3] * W2s[(k + 3) * HIDC + f];
            }
            float acc = (a0 + a1) + (a2 + a3);
            Ap[(long)i * HIDC + f] = acc * dinv[i];
        }
    }
}

// ---------------- pooling (batch sorted -> run-length local accumulate) ----------------
__global__ void k_pool_init(float* pooled, float* cnt) {
    int i = blockIdx.x * 256 + threadIdx.x;
    if (i < NG * HIDC) pooled[i] = 0.f;
    if (i < NG) cnt[i] = 0.f;
}

__global__ __launch_bounds__(128) void k_pool(const float* __restrict__ B,
                                              const float* __restrict__ b2,
                                              const int* __restrict__ batch,
                                              float* pooled, float* cnt) {
    int f = threadIdx.x;
    int start = blockIdx.x * 64;
    int end = start + 64 < NN ? start + 64 : NN;
    float sum = 0.f;
    int gcur = -1, cl = 0;
    for (int i = start; i < end; ++i) {
        int g = batch[i];
        if (g != gcur) {
            if (gcur >= 0) {
                unsafeAtomicAdd(&pooled[gcur * HIDC + f], sum);
                if (f == 0) unsafeAtomicAdd(&cnt[gcur], (float)cl);
            }
            gcur = g; sum = 0.f; cl = 0;
        }
        float h = B[(long)i * HIDC + f] + b2[f];
        sum += h > 0.f ? h : 0.f;
        cl++;
    }
    if (gcur >= 0) {
        unsafeAtomicAdd(&pooled[gcur * HIDC + f], sum);
        if (f == 0) unsafeAtomicAdd(&cnt[gcur], (float)cl);
    }
}

// ---------------- head ----------------
__global__ __launch_bounds__(128) void k_final(const float* __restrict__ pooled,
                                               const float* __restrict__ cnt,
                                               const float* __restrict__ Wc,
                                               const float* __restrict__ bc,
                                               float* __restrict__ out) {
    __shared__ float v0s[HIDC], v1s[HIDC];
    int g = blockIdx.x, f = threadIdx.x;
    float c = cnt[g]; c = c > 1.f ? c : 1.f;
    float val = pooled[g * HIDC + f] / c;
    v0s[f] = val * Wc[f * OUTC + 0];
    v1s[f] = val * Wc[f * OUTC + 1];
    __syncthreads();
    if (f < 2) {
        const float* arr = (f == 0) ? v0s : v1s;
        float s = 0.f;
        for (int k = 0; k < HIDC; ++k) s += arr[k];
        out[g * OUTC + f] = s + bc[f];
    }
}

extern "C" void kernel_launch(void* const* d_in, const int* in_sizes, int n_in,
                              void* d_out, int out_size, void* d_ws, size_t ws_size,
                              hipStream_t stream) {
    const float* x     = (const float*)d_in[0];
    const int*   ei    = (const int*)d_in[1];   // [2, NE] int32
    const int*   batch = (const int*)d_in[2];
    const float* W1    = (const float*)d_in[3];
    const float* b1    = (const float*)d_in[4];
    const float* W2    = (const float*)d_in[5];
    const float* b2    = (const float*)d_in[6];
    const float* Wc    = (const float*)d_in[7];
    const float* bc    = (const float*)d_in[8];
    float* out = (float*)d_out;

    char* ws = (char*)d_ws;
    size_t off = 0;
    auto alloc = [&](size_t bytes) { void* p = ws + off; off += (bytes + 255) / 256 * 256; return p; };
    float* Ap      = (float*)alloc((size_t)NN * HIDC * 4);
    float* B       = (float*)alloc((size_t)NN * HIDC * 4);
    float* dinv    = (float*)alloc((size_t)NN * 4);
    int*   counts  = (int*)alloc((size_t)NN * 4);
    int*   offsets = (int*)alloc((size_t)(NN + 1) * 4);
    int*   cursor  = (int*)alloc((size_t)NN * 4);
    int*   csr_src = (int*)alloc((size_t)NE * 4);
    int*   bsum    = (int*)alloc((size_t)NB_SCAN * 4);
    int*   boff    = (int*)alloc((size_t)NB_SCAN * 4);
    float* pooled  = (float*)alloc((size_t)NG * HIDC * 4);
    float* cnt     = (float*)alloc((size_t)NG * 4);

    const int* row = ei;        // sources
    const int* col = ei + NE;   // targets

    // CSR build (by target)
    k_zero<<<(NN + 255) / 256, 256, 0, stream>>>(counts);
    k_hist<<<(NE + 255) / 256, 256, 0, stream>>>(col, counts);
    k_dinv<<<(NN + 255) / 256, 256, 0, stream>>>(counts, dinv);
    k_scanA<<<NB_SCAN, 256, 0, stream>>>(counts, bsum);
    k_scanB<<<1, 128, 0, stream>>>(bsum, boff, offsets);
    k_scanC<<<NB_SCAN, 256, 0, stream>>>(counts, boff, offsets, cursor);
    k_fill<<<(NE + 255) / 256, 256, 0, stream>>>(row, col, cursor, csr_src);

    // layer 1
    k_xw1<<<(NN + 1) / 2, 256, 0, stream>>>(x, W1, dinv, Ap);
    k_gather<<<(NN * 64 + 255) / 256, 256, 0, stream>>>(Ap, csr_src, offsets, dinv, B);

    // layer 2
    k_layer2<<<512, 256, 0, stream>>>(B, b1, W2, dinv, Ap);
    k_gather<<<(NN * 64 + 255) / 256, 256, 0, stream>>>(Ap, csr_src, offsets, dinv, B);

    // pool + head
    k_pool_init<<<(NG * HIDC + 255) / 256, 256, 0, stream>>>(pooled, cnt);
    k_pool<<<(NN + 63) / 64, 128, 0, stream>>>(B, b2, batch, pooled, cnt);
    k_final<<<NG, 128, 0, stream>>>(pooled, cnt, Wc, bc, out);
}

// Round 4
// 490.147 us; speedup vs baseline: 3.5364x; 1.4620x over previous
//
#include <hip/hip_runtime.h>

#define NN 100000
#define NE 1600000
#define NG 64
#define HIDC 128
#define INC 9
#define OUTC 2
#define SCAN_CHUNK 1024
#define NB_SCAN ((NN + SCAN_CHUNK - 1) / SCAN_CHUNK)  // 98

typedef unsigned int u32;

// ---- bf16 pack/unpack (round-to-nearest-even), 2 feats per u32 (lo=even feat) ----
__device__ inline float bf_lo(u32 u) { return __uint_as_float(u << 16); }
__device__ inline float bf_hi(u32 u) { return __uint_as_float(u & 0xFFFF0000u); }
__device__ inline u32 f2bf(float x) {
    u32 u = __float_as_uint(x);
    return (u + 0x7FFFu + ((u >> 16) & 1u)) >> 16;
}
__device__ inline u32 packbf(float a, float b) { return f2bf(a) | (f2bf(b) << 16); }

// ---------------- CSR build: counting sort by target (col) ----------------
__global__ void k_zero(int* counts) {
    int i = blockIdx.x * 256 + threadIdx.x;
    if (i < NN) counts[i] = 0;
}

__global__ void k_hist(const int* __restrict__ col, int* counts) {
    int e = blockIdx.x * 256 + threadIdx.x;
    if (e < NE) atomicAdd(&counts[col[e]], 1);
}

__global__ void k_dinv(const int* __restrict__ counts, float* dinv) {
    int i = blockIdx.x * 256 + threadIdx.x;
    if (i < NN) dinv[i] = rsqrtf((float)(counts[i] + 1));  // +1 self-loop
}

__global__ __launch_bounds__(256) void k_scanA(const int* __restrict__ counts, int* __restrict__ bsum) {
    __shared__ int lds[256];
    int b = blockIdx.x, t = threadIdx.x;
    int idx = b * SCAN_CHUNK + t * 4;
    int s = 0;
#pragma unroll
    for (int j = 0; j < 4; ++j)
        if (idx + j < NN) s += counts[idx + j];
    lds[t] = s;
    __syncthreads();
    for (int d = 128; d > 0; d >>= 1) {
        if (t < d) lds[t] += lds[t + d];
        __syncthreads();
    }
    if (t == 0) bsum[b] = lds[0];
}

__global__ __launch_bounds__(128) void k_scanB(const int* __restrict__ bsum,
                                               int* __restrict__ boff,
                                               int* __restrict__ offsets) {
    __shared__ int lds[128];
    int t = threadIdx.x;
    int v = (t < NB_SCAN) ? bsum[t] : 0;
    lds[t] = v;
    __syncthreads();
    for (int d = 1; d < 128; d <<= 1) {
        int u = (t >= d) ? lds[t - d] : 0;
        __syncthreads();
        lds[t] += u;
        __syncthreads();
    }
    if (t < NB_SCAN) boff[t] = lds[t] - v;  // exclusive
    if (t == NB_SCAN - 1) offsets[NN] = lds[t];
}

__global__ __launch_bounds__(256) void k_scanC(const int* __restrict__ counts,
                                               const int* __restrict__ boff,
                                               int* __restrict__ offsets,
                                               int* __restrict__ cursor) {
    __shared__ int lds[256];
    int b = blockIdx.x, t = threadIdx.x;
    int idx = b * SCAN_CHUNK + t * 4;
    int c[4];
#pragma unroll
    for (int j = 0; j < 4; ++j) c[j] = (idx + j < NN) ? counts[idx + j] : 0;
    int tot = c[0] + c[1] + c[2] + c[3];
    lds[t] = tot;
    __syncthreads();
    for (int d = 1; d < 256; d <<= 1) {
        int u = (t >= d) ? lds[t - d] : 0;
        __syncthreads();
        lds[t] += u;
        __syncthreads();
    }
    int p = boff[b] + lds[t] - tot;
#pragma unroll
    for (int j = 0; j < 4; ++j) {
        if (idx + j < NN) {
            offsets[idx + j] = p;
            cursor[idx + j] = p;
            p += c[j];
        }
    }
}

__global__ void k_fill(const int* __restrict__ row, const int* __restrict__ col,
                       int* cursor, int* __restrict__ csr_src) {
    int e = blockIdx.x * 256 + threadIdx.x;
    if (e < NE) {
        int p = atomicAdd(&cursor[col[e]], 1);
        csr_src[p] = row[e];
    }
}

// ---------------- layer-1 dense: Ap = bf16( (x@W1) * dinv ) ----------------
__global__ __launch_bounds__(256) void k_xw1(const float* __restrict__ x,
                                             const float* __restrict__ W1,
                                             const float* __restrict__ dinv,
                                             u32* __restrict__ Ap2) {
    int tid = threadIdx.x;
    int i = blockIdx.x * 4 + (tid >> 6);
    int j = tid & 63;  // feat pair -> feats 2j, 2j+1
    if (i >= NN) return;
    float acc0 = 0.f, acc1 = 0.f;
#pragma unroll
    for (int k = 0; k < INC; ++k) {
        float xv = x[i * INC + k];
        acc0 += xv * W1[k * HIDC + 2 * j];
        acc1 += xv * W1[k * HIDC + 2 * j + 1];
    }
    float di = dinv[i];
    Ap2[(long)i * 64 + j] = packbf(acc0 * di, acc1 * di);
}

// ---------------- gather: B[i] = bf16( dinv[i] * (Ap[i] + sum Ap[src]) ) ----------------
// one 64-lane wave per node, one u32 (2 bf16) per lane -> 256B row reads
__global__ __launch_bounds__(256) void k_gather(const u32* __restrict__ Ap2,
                                                const int* __restrict__ csr_src,
                                                const int* __restrict__ offsets,
                                                const float* __restrict__ dinv,
                                                u32* __restrict__ B2) {
    int i = (blockIdx.x * 256 + threadIdx.x) >> 6;
    if (i >= NN) return;
    int lane = threadIdx.x & 63;
    long base = (long)i * 64 + lane;
    u32 a = Ap2[base];
    float acc0 = bf_lo(a), acc1 = bf_hi(a);
    int beg = offsets[i], end = offsets[i + 1];
    int e = beg;
    for (; e + 4 <= end; e += 4) {
        int s0 = csr_src[e], s1 = csr_src[e + 1], s2 = csr_src[e + 2], s3 = csr_src[e + 3];
        u32 v0 = Ap2[(long)s0 * 64 + lane];
        u32 v1 = Ap2[(long)s1 * 64 + lane];
        u32 v2 = Ap2[(long)s2 * 64 + lane];
        u32 v3 = Ap2[(long)s3 * 64 + lane];
        acc0 += (bf_lo(v0) + bf_lo(v1)) + (bf_lo(v2) + bf_lo(v3));
        acc1 += (bf_hi(v0) + bf_hi(v1)) + (bf_hi(v2) + bf_hi(v3));
    }
    for (; e < end; ++e) {
        u32 v = Ap2[(long)csr_src[e] * 64 + lane];
        acc0 += bf_lo(v);
        acc1 += bf_hi(v);
    }
    float di = dinv[i];
    B2[base] = packbf(acc0 * di, acc1 * di);
}

// ---------------- layer-2 dense: h=relu(B+b1); Ap = bf16((h@W2)*dinv) ----------------
// 64 nodes/block, 256 threads, each thread: 4 nodes x 8 cols register tile.
__global__ __launch_bounds__(256) void k_layer2(const u32* __restrict__ B2,
                                                const float* __restrict__ b1,
                                                const float* __restrict__ W2,
                                                const float* __restrict__ dinv,
                                                u32* __restrict__ Ap2) {
    __shared__ float hs[64][HIDC + 1];  // +1 pad: conflict-free broadcast reads
    __shared__ float W2s[32][HIDC];     // one 32-k tile
    int t = threadIdx.x;
    int nb = blockIdx.x * 64;
    // load h = relu(B + b1), coalesced global, strided LDS write (2-way, free)
    int j = t & 63;
    float bb0 = b1[2 * j], bb1 = b1[2 * j + 1];
    for (int n = t >> 6; n < 64; n += 4) {
        int node = nb + n;
        u32 u = (node < NN) ? B2[(long)node * 64 + j] : 0u;
        float h0 = bf_lo(u) + bb0;
        float h1 = bf_hi(u) + bb1;
        hs[n][2 * j] = h0 > 0.f ? h0 : 0.f;
        hs[n][2 * j + 1] = h1 > 0.f ? h1 : 0.f;
    }
    int cg = t & 15, ng = t >> 4;
    int n0 = ng * 4, c0 = cg * 8;
    float acc[4][8] = {};
    for (int kt = 0; kt < 4; ++kt) {
        __syncthreads();
        for (int idx = t; idx < 1024; idx += 256)
            ((float4*)W2s)[idx] = ((const float4*)W2)[kt * 1024 + idx];
        __syncthreads();
#pragma unroll 8
        for (int k = 0; k < 32; ++k) {
            int kk = kt * 32 + k;
            float a0 = hs[n0 + 0][kk], a1 = hs[n0 + 1][kk];
            float a2 = hs[n0 + 2][kk], a3 = hs[n0 + 3][kk];
            float4 w0 = *(const float4*)&W2s[k][c0];
            float4 w1 = *(const float4*)&W2s[k][c0 + 4];
            acc[0][0] += a0 * w0.x; acc[0][1] += a0 * w0.y; acc[0][2] += a0 * w0.z; acc[0][3] += a0 * w0.w;
            acc[0][4] += a0 * w1.x; acc[0][5] += a0 * w1.y; acc[0][6] += a0 * w1.z; acc[0][7] += a0 * w1.w;
            acc[1][0] += a1 * w0.x; acc[1][1] += a1 * w0.y; acc[1][2] += a1 * w0.z; acc[1][3] += a1 * w0.w;
            acc[1][4] += a1 * w1.x; acc[1][5] += a1 * w1.y; acc[1][6] += a1 * w1.z; acc[1][7] += a1 * w1.w;
            acc[2][0] += a2 * w0.x; acc[2][1] += a2 * w0.y; acc[2][2] += a2 * w0.z; acc[2][3] += a2 * w0.w;
            acc[2][4] += a2 * w1.x; acc[2][5] += a2 * w1.y; acc[2][6] += a2 * w1.z; acc[2][7] += a2 * w1.w;
            acc[3][0] += a3 * w0.x; acc[3][1] += a3 * w0.y; acc[3][2] += a3 * w0.z; acc[3][3] += a3 * w0.w;
            acc[3][4] += a3 * w1.x; acc[3][5] += a3 * w1.y; acc[3][6] += a3 * w1.z; acc[3][7] += a3 * w1.w;
        }
    }
#pragma unroll
    for (int r = 0; r < 4; ++r) {
        int node = nb + n0 + r;
        if (node < NN) {
            float di = dinv[node];
            uint4 o;
            o.x = packbf(acc[r][0] * di, acc[r][1] * di);
            o.y = packbf(acc[r][2] * di, acc[r][3] * di);
            o.z = packbf(acc[r][4] * di, acc[r][5] * di);
            o.w = packbf(acc[r][6] * di, acc[r][7] * di);
            ((uint4*)Ap2)[(long)node * 16 + cg] = o;
        }
    }
}

// ---------------- pooling (batch sorted -> run-length local accumulate) ----------------
__global__ void k_pool_init(float* pooled, float* cnt) {
    int i = blockIdx.x * 256 + threadIdx.x;
    if (i < NG * HIDC) pooled[i] = 0.f;
    if (i < NG) cnt[i] = 0.f;
}

__global__ __launch_bounds__(64) void k_pool(const u32* __restrict__ B2,
                                             const float* __restrict__ b2,
                                             const int* __restrict__ batch,
                                             float* pooled, float* cnt) {
    int f = threadIdx.x;  // feat pair
    int start = blockIdx.x * 64;
    int end = start + 64 < NN ? start + 64 : NN;
    float bb0 = b2[2 * f], bb1 = b2[2 * f + 1];
    float s0 = 0.f, s1 = 0.f;
    int gcur = -1, cl = 0;
    for (int i = start; i < end; ++i) {
        int g = batch[i];
        if (g != gcur) {
            if (gcur >= 0) {
                unsafeAtomicAdd(&pooled[gcur * HIDC + 2 * f], s0);
                unsafeAtomicAdd(&pooled[gcur * HIDC + 2 * f + 1], s1);
                if (f == 0) unsafeAtomicAdd(&cnt[gcur], (float)cl);
            }
            gcur = g; s0 = s1 = 0.f; cl = 0;
        }
        u32 u = B2[(long)i * 64 + f];
        float h0 = bf_lo(u) + bb0;
        float h1 = bf_hi(u) + bb1;
        s0 += h0 > 0.f ? h0 : 0.f;
        s1 += h1 > 0.f ? h1 : 0.f;
        cl++;
    }
    if (gcur >= 0) {
        unsafeAtomicAdd(&pooled[gcur * HIDC + 2 * f], s0);
        unsafeAtomicAdd(&pooled[gcur * HIDC + 2 * f + 1], s1);
        if (f == 0) unsafeAtomicAdd(&cnt[gcur], (float)cl);
    }
}

// ---------------- head ----------------
__global__ __launch_bounds__(128) void k_final(const float* __restrict__ pooled,
                                               const float* __restrict__ cnt,
                                               const float* __restrict__ Wc,
                                               const float* __restrict__ bc,
                                               float* __restrict__ out) {
    __shared__ float v0s[HIDC], v1s[HIDC];
    int g = blockIdx.x, f = threadIdx.x;
    float c = cnt[g]; c = c > 1.f ? c : 1.f;
    float val = pooled[g * HIDC + f] / c;
    v0s[f] = val * Wc[f * OUTC + 0];
    v1s[f] = val * Wc[f * OUTC + 1];
    __syncthreads();
    if (f < 2) {
        const float* arr = (f == 0) ? v0s : v1s;
        float s = 0.f;
        for (int k = 0; k < HIDC; ++k) s += arr[k];
        out[g * OUTC + f] = s + bc[f];
    }
}

extern "C" void kernel_launch(void* const* d_in, const int* in_sizes, int n_in,
                              void* d_out, int out_size, void* d_ws, size_t ws_size,
                              hipStream_t stream) {
    const float* x     = (const float*)d_in[0];
    const int*   ei    = (const int*)d_in[1];   // [2, NE] int32
    const int*   batch = (const int*)d_in[2];
    const float* W1    = (const float*)d_in[3];
    const float* b1    = (const float*)d_in[4];
    const float* W2    = (const float*)d_in[5];
    const float* b2    = (const float*)d_in[6];
    const float* Wc    = (const float*)d_in[7];
    const float* bc    = (const float*)d_in[8];
    float* out = (float*)d_out;

    char* ws = (char*)d_ws;
    size_t off = 0;
    auto alloc = [&](size_t bytes) { void* p = ws + off; off += (bytes + 255) / 256 * 256; return p; };
    u32*   Ap2     = (u32*)alloc((size_t)NN * 64 * 4);   // bf16 x2 packed
    u32*   B2      = (u32*)alloc((size_t)NN * 64 * 4);
    float* dinv    = (float*)alloc((size_t)NN * 4);
    int*   counts  = (int*)alloc((size_t)NN * 4);
    int*   offsets = (int*)alloc((size_t)(NN + 1) * 4);
    int*   cursor  = (int*)alloc((size_t)NN * 4);
    int*   csr_src = (int*)alloc((size_t)NE * 4);
    int*   bsum    = (int*)alloc((size_t)NB_SCAN * 4);
    int*   boff    = (int*)alloc((size_t)NB_SCAN * 4);
    float* pooled  = (float*)alloc((size_t)NG * HIDC * 4);
    float* cnt     = (float*)alloc((size_t)NG * 4);

    const int* row = ei;        // sources
    const int* col = ei + NE;   // targets

    // CSR build (by target)
    k_zero<<<(NN + 255) / 256, 256, 0, stream>>>(counts);
    k_hist<<<(NE + 255) / 256, 256, 0, stream>>>(col, counts);
    k_dinv<<<(NN + 255) / 256, 256, 0, stream>>>(counts, dinv);
    k_scanA<<<NB_SCAN, 256, 0, stream>>>(counts, bsum);
    k_scanB<<<1, 128, 0, stream>>>(bsum, boff, offsets);
    k_scanC<<<NB_SCAN, 256, 0, stream>>>(counts, boff, offsets, cursor);
    k_fill<<<(NE + 255) / 256, 256, 0, stream>>>(row, col, cursor, csr_src);

    // layer 1
    k_xw1<<<(NN + 3) / 4, 256, 0, stream>>>(x, W1, dinv, Ap2);
    k_gather<<<(NN * 64 + 255) / 256, 256, 0, stream>>>(Ap2, csr_src, offsets, dinv, B2);

    // layer 2
    k_layer2<<<(NN + 63) / 64, 256, 0, stream>>>(B2, b1, W2, dinv, Ap2);
    k_gather<<<(NN * 64 + 255) / 256, 256, 0, stream>>>(Ap2, csr_src, offsets, dinv, B2);

    // pool + head
    k_pool_init<<<(NG * HIDC + 255) / 256, 256, 0, stream>>>(pooled, cnt);
    k_pool<<<(NN + 63) / 64, 64, 0, stream>>>(B2, b2, batch, pooled, cnt);
    k_final<<<NG, 128, 0, stream>>>(pooled, cnt, Wc, bc, out);
}